// Round 1
// baseline (229.718 us; speedup 1.0000x reference)
//
#include <hip/hip_runtime.h>

// RoPE, interleaved-pair convention:
//   out[2k]   = x[2k]*cos[pos][k] - x[2k+1]*sin[pos][k]
//   out[2k+1] = x[2k]*sin[pos][k] + x[2k+1]*cos[pos][k]
// x: (B,H,S,128) fp32 contiguous. One thread per float4 (2 pairs).
// 32 float4 per row of D=128.

template <bool POW2>
__global__ __launch_bounds__(256) void rope_kernel(
    const float4* __restrict__ x,
    const float2* __restrict__ sin_c,   // (MAX_SEQ_LEN, 64) viewed as (..,32) float2
    const float2* __restrict__ cos_c,
    const int*    __restrict__ tok_pos, // (S,)
    float4*       __restrict__ out,
    int n4, int s_div)                  // s_div = S-1 (mask) if POW2 else S
{
    int idx = blockIdx.x * blockDim.x + threadIdx.x;
    if (idx >= n4) return;

    int row = idx >> 5;      // which (b,h,s) row; 32 float4 per row
    int j   = idx & 31;      // float4 within row -> pairs 2j, 2j+1
    int s   = POW2 ? (row & s_div) : (row % s_div);
    int p   = tok_pos[s];

    float2 c  = cos_c[p * 32 + j];  // cos row: 64 floats = 32 float2
    float2 sn = sin_c[p * 32 + j];

    float4 v = x[idx];
    float4 o;
    o.x = v.x * c.x - v.y * sn.x;
    o.y = v.x * sn.x + v.y * c.x;
    o.z = v.z * c.y - v.w * sn.y;
    o.w = v.z * sn.y + v.w * c.y;
    out[idx] = o;
}

extern "C" void kernel_launch(void* const* d_in, const int* in_sizes, int n_in,
                              void* d_out, int out_size, void* d_ws, size_t ws_size,
                              hipStream_t stream) {
    // setup_inputs order: x, sin_cached, cos_cached, token_positions
    const float4* x     = (const float4*)d_in[0];
    const float2* sin_c = (const float2*)d_in[1];
    const float2* cos_c = (const float2*)d_in[2];
    const int*    tpos  = (const int*)d_in[3];
    float4*       out   = (float4*)d_out;

    const int S  = in_sizes[3];       // 4096
    const int n4 = out_size / 4;      // one thread per float4

    const int block = 256;
    const int grid  = (n4 + block - 1) / block;

    if ((S & (S - 1)) == 0) {
        rope_kernel<true><<<grid, block, 0, stream>>>(x, sin_c, cos_c, tpos, out, n4, S - 1);
    } else {
        rope_kernel<false><<<grid, block, 0, stream>>>(x, sin_c, cos_c, tpos, out, n4, S);
    }
}